// Round 5
// baseline (130.539 us; speedup 1.0000x reference)
//
#include <hip/hip_runtime.h>

// multi_triples_lstm v19: v18 (rolled, barrier-free) + phase-batched chains
// + merged reciprocals.
// Post-mortem model: duration tracks per-SIMD executed work at a constant
// ~40% pipe efficiency across ALL prior structures (v14 32w/CU barriers,
// v15/v18 8w/CU barrier-free, v16/v17 bigger bodies). Trans stream is the
// largest consumer (56 trans/wave-step x 8cyc). v19 tests whether the 60%
// stall is compiler chain-serialization: (1) all 16 leaf exps batched so
// their latencies overlap, (2) merged rcp (v16-validated: rcp(a*b) + 2 muls
// recovers 1/a,1/b) cuts 16 rcp -> 8 per wave-step, (3) unroll 2 so step t's
// chain tail overlaps step t+1's independent x-MFMAs.
#define XSTRIDE 1072
#define ZOFF    (16 * XSTRIDE)
#define LDS_BYTES (ZOFF + 32)

typedef _Float16 f16x8 __attribute__((ext_vector_type(8)));
typedef __fp16   fp16x2 __attribute__((ext_vector_type(2)));
typedef float    f32x4 __attribute__((ext_vector_type(4)));
typedef float    f32x2 __attribute__((ext_vector_type(2)));

#define LOG2E     1.44269504088896f
#define TWO_LOG2E 2.88539008177793f

__global__ __launch_bounds__(64, 2)
void lstm_fused(const int* __restrict__ objs,
                const float* __restrict__ boxes,
                const int* __restrict__ preds,
                const int* __restrict__ subj,
                const float* __restrict__ obj_emb,
                const float* __restrict__ pred_emb,
                const float* __restrict__ W_ih,
                const float* __restrict__ W_hh,
                const float* __restrict__ b_ih,
                const float* __restrict__ b_hh,
                const float* __restrict__ fc2_W,
                const float* __restrict__ fc2_b,
                float* __restrict__ out)
{
    extern __shared__ char smem[];
    const int lane = threadIdx.x;        // 0..63
    const int quad = lane >> 4;          // 0..3: K-slice of MFMA frags
    const int cidx = lane & 15;          // batch column

    if (lane < 8) ((int*)(smem + ZOFF))[lane] = 0;

    // ---- stage x features (fp16) for this wave's 16 batches ----
    {
        const int b = lane >> 2;
        const int j = lane & 3;
        const long gb = (long)blockIdx.x * 16 + b;
        const int* orow = objs + gb * 32;
        const int* prow = preds + gb * 32;
        const int* srow = subj + gb * 32;
        const float* brow = boxes + gb * 128;
        char* xrow = smem + b * XSTRIDE;
        #pragma unroll
        for (int tt = 0; tt < 8; ++tt) {
            int t = j + tt * 4;
            int o = orow[t], p = prow[t], sv = srow[t];
            const float* eo = obj_emb + o * 5;
            const float* ep = pred_emb + p * 5;
            float4 bx = *(const float4*)(brow + t * 4);
            f16x8 lo, hi;
            lo[0]=(_Float16)eo[0]; lo[1]=(_Float16)eo[1]; lo[2]=(_Float16)eo[2];
            lo[3]=(_Float16)eo[3]; lo[4]=(_Float16)eo[4];
            lo[5]=(_Float16)ep[0]; lo[6]=(_Float16)ep[1]; lo[7]=(_Float16)ep[2];
            hi[0]=(_Float16)ep[3]; hi[1]=(_Float16)ep[4];
            hi[2]=(_Float16)(sv==0 ? 1.0f : 0.0f);
            hi[3]=(_Float16)(sv==1 ? 1.0f : 0.0f);
            hi[4]=(_Float16)bx.x; hi[5]=(_Float16)bx.y;
            hi[6]=(_Float16)bx.z; hi[7]=(_Float16)bx.w;
            *(f16x8*)(xrow + t * 32)      = lo;
            *(f16x8*)(xrow + t * 32 + 16) = hi;
        }
    }

    // ---- W fragments + bias ----
    f16x8 WH[8], WX[8];
    f32x4 bias[8];
    #pragma unroll
    for (int a = 0; a < 8; ++a) {
        const int gate = a >> 1;
        const float scale = (gate == 2) ? TWO_LOG2E : -LOG2E;
        const int n = gate * 32 + 8 * (cidx >> 2) + 4 * (a & 1) + (cidx & 3);
        const float* wr = W_hh + n * 32 + quad * 8;
        float4 w0 = *(const float4*)(wr);
        float4 w1 = *(const float4*)(wr + 4);
        f16x8 h8;
        h8[0]=(_Float16)(w0.x*scale); h8[1]=(_Float16)(w0.y*scale);
        h8[2]=(_Float16)(w0.z*scale); h8[3]=(_Float16)(w0.w*scale);
        h8[4]=(_Float16)(w1.x*scale); h8[5]=(_Float16)(w1.y*scale);
        h8[6]=(_Float16)(w1.z*scale); h8[7]=(_Float16)(w1.w*scale);
        WH[a] = h8;
        f16x8 x8;
        if (quad < 2) {
            const float* xr = W_ih + n * 16 + quad * 8;
            float4 u0 = *(const float4*)(xr);
            float4 u1 = *(const float4*)(xr + 4);
            x8[0]=(_Float16)(u0.x*scale); x8[1]=(_Float16)(u0.y*scale);
            x8[2]=(_Float16)(u0.z*scale); x8[3]=(_Float16)(u0.w*scale);
            x8[4]=(_Float16)(u1.x*scale); x8[5]=(_Float16)(u1.y*scale);
            x8[6]=(_Float16)(u1.z*scale); x8[7]=(_Float16)(u1.w*scale);
        } else {
            #pragma unroll
            for (int jj = 0; jj < 8; ++jj) x8[jj] = (_Float16)0.0f;
        }
        WX[a] = x8;
        const int nb = gate * 32 + 8 * quad + 4 * (a & 1);
        float4 bi = *(const float4*)(b_ih + nb);
        float4 bh = *(const float4*)(b_hh + nb);
        f32x4 bb = {(bi.x+bh.x)*scale, (bi.y+bh.y)*scale,
                    (bi.z+bh.z)*scale, (bi.w+bh.w)*scale};
        bias[a] = bb;
    }

    __syncthreads();   // staging visible

    // ---- recurrence: barrier-free ----
    const bool qlow = (quad < 2);
    int xaddr = qlow ? (cidx * XSTRIDE + quad * 16) : ZOFF;
    const int xinc = qlow ? 32 : 0;

    f16x8 xfrag = *(const f16x8*)(smem + xaddr); xaddr += xinc;
    f32x4 accp[8];
    #pragma unroll
    for (int a = 0; a < 8; ++a)
        accp[a] = __builtin_amdgcn_mfma_f32_16x16x32_f16(WX[a], xfrag, bias[a], 0, 0, 0);

    union { int i[4]; f16x8 v; } hf;
    hf.i[0]=0; hf.i[1]=0; hf.i[2]=0; hf.i[3]=0;
    const f32x2 zz = {0.0f, 0.0f};
    f32x2 cst[4] = {zz, zz, zz, zz};
    f32x2 hv[4];
    const f32x2 one = {1.0f, 1.0f};

    #pragma unroll 2
    for (int t = 0; t < 32; ++t) {
        f32x4 acc[8];
        #pragma unroll
        for (int a = 0; a < 8; ++a)
            acc[a] = __builtin_amdgcn_mfma_f32_16x16x32_f16(WH[a], hf.v, accp[a], 0, 0, 0);

        f16x8 xn = *(const f16x8*)(smem + xaddr); xaddr += xinc;

        // ---- Phase A: all 16 leaf exps batched (latencies overlap) ----
        f32x2 Ei[4], Ef[4], Eg[4], Eo[4];
        #pragma unroll
        for (int cc = 0; cc < 4; ++cc) {
            const int sel = cc >> 1;
            const int r0  = (cc & 1) << 1;
            Ei[cc].x = __builtin_amdgcn_exp2f(acc[0+sel][r0]);
            Ei[cc].y = __builtin_amdgcn_exp2f(acc[0+sel][r0+1]);
            Ef[cc].x = __builtin_amdgcn_exp2f(acc[2+sel][r0]);
            Ef[cc].y = __builtin_amdgcn_exp2f(acc[2+sel][r0+1]);
            Eg[cc].x = __builtin_amdgcn_exp2f(acc[4+sel][r0]);
            Eg[cc].y = __builtin_amdgcn_exp2f(acc[4+sel][r0+1]);
            Eo[cc].x = __builtin_amdgcn_exp2f(acc[6+sel][r0]);
            Eo[cc].y = __builtin_amdgcn_exp2f(acc[6+sel][r0+1]);
        }

        // ---- Phase B: algebra to den/nn for all chains ----
        f32x2 den[4], nn[4];
        #pragma unroll
        for (int cc = 0; cc < 4; ++cc) {
            f32x2 t1  = Ei[cc] + one;
            f32x2 dig = t1 * Eg[cc] + t1;               // (1+Ei)(1+Eg)
            f32x2 tf  = Ef[cc] + one;
            nn[cc]  = (Eg[cc] - one) * tf + cst[cc] * dig;
            den[cc] = tf * dig;
        }

        // ---- Phase C: merged rcp pairs {0,1},{2,3}; new c ----
        f32x2 cv[4];
        #pragma unroll
        for (int pp = 0; pp < 2; ++pp) {
            f32x2 P = den[2*pp] * den[2*pp+1];
            f32x2 R = {__builtin_amdgcn_rcpf(P.x), __builtin_amdgcn_rcpf(P.y)};
            cv[2*pp]   = nn[2*pp]   * (R * den[2*pp+1]);
            cv[2*pp+1] = nn[2*pp+1] * (R * den[2*pp]);
            cst[2*pp]   = cv[2*pp];
            cst[2*pp+1] = cv[2*pp+1];
        }

        // ---- Phase D: all 8 Ec exps batched ----
        f32x2 Ec[4];
        #pragma unroll
        for (int cc = 0; cc < 4; ++cc) {
            Ec[cc].x = __builtin_amdgcn_exp2f(cv[cc].x * TWO_LOG2E);
            Ec[cc].y = __builtin_amdgcn_exp2f(cv[cc].y * TWO_LOG2E);
        }

        // ---- Phase E: dh, merged rcp, h, pack ----
        f32x2 dh[4];
        #pragma unroll
        for (int cc = 0; cc < 4; ++cc) {
            f32x2 to = Eo[cc] + one;
            dh[cc] = to * Ec[cc] + to;                  // (1+Eo)(1+Ec)
        }
        #pragma unroll
        for (int pp = 0; pp < 2; ++pp) {
            f32x2 Q = dh[2*pp] * dh[2*pp+1];
            f32x2 S = {__builtin_amdgcn_rcpf(Q.x), __builtin_amdgcn_rcpf(Q.y)};
            hv[2*pp]   = (Ec[2*pp]   - one) * (S * dh[2*pp+1]);
            hv[2*pp+1] = (Ec[2*pp+1] - one) * (S * dh[2*pp]);
            union { fp16x2 h; int i; } pk0, pk1;
            pk0.h = __builtin_amdgcn_cvt_pkrtz(hv[2*pp].x,   hv[2*pp].y);
            pk1.h = __builtin_amdgcn_cvt_pkrtz(hv[2*pp+1].x, hv[2*pp+1].y);
            hf.i[2*pp]   = pk0.i;
            hf.i[2*pp+1] = pk1.i;
        }

        #pragma unroll
        for (int a = 0; a < 8; ++a)
            accp[a] = __builtin_amdgcn_mfma_f32_16x16x32_f16(WX[a], xn, bias[a], 0, 0, 0);
    }

    // ---- fc2 epilogue (wave-local) ----
    __syncthreads();
    {
        char* s0 = smem + cidx * 144 + quad * 32;
        float4 lo4 = {hv[0].x, hv[0].y, hv[1].x, hv[1].y};
        float4 hi4 = {hv[2].x, hv[2].y, hv[3].x, hv[3].y};
        *(float4*)s0        = lo4;
        *(float4*)(s0 + 16) = hi4;
    }
    __syncthreads();
    {
        const int b = lane >> 2, j = lane & 3;
        const float* hrow = (const float*)(smem + b * 144);
        const float* fw = fc2_W + j * 32;
        float s = fc2_b[j];
        #pragma unroll
        for (int k = 0; k < 8; ++k) {
            float4 hvv = *(const float4*)(hrow + k * 4);
            float4 wv4 = *(const float4*)(fw + k * 4);
            s += wv4.x*hvv.x + wv4.y*hvv.y + wv4.z*hvv.z + wv4.w*hvv.w;
        }
        s = fminf(fmaxf(s, 0.0f), 1.0f);
        out[(long)blockIdx.x * 64 + lane] = s;
    }
}

extern "C" void kernel_launch(void* const* d_in, const int* in_sizes, int n_in,
                              void* d_out, int out_size, void* d_ws, size_t ws_size,
                              hipStream_t stream)
{
    // inputs: 0 objs(i32) 1 boxes(f32) 2 preds(i32) 3 subj(i32) 4 target(unused)
    //         5 obj_emb 6 pred_emb 7 W_ih 8 W_hh 9 b_ih 10 b_hh 11 fc2_W 12 fc2_b
    lstm_fused<<<2048, 64, LDS_BYTES, stream>>>(
        (const int*)d_in[0], (const float*)d_in[1], (const int*)d_in[2],
        (const int*)d_in[3],
        (const float*)d_in[5], (const float*)d_in[6],
        (const float*)d_in[7], (const float*)d_in[8],
        (const float*)d_in[9], (const float*)d_in[10],
        (const float*)d_in[11], (const float*)d_in[12],
        (float*)d_out);
}

// Round 6
// 129.587 us; speedup vs baseline: 1.0073x; 1.0073x over previous
//
#include <hip/hip_runtime.h>

// multi_triples_lstm v20: v18 per-wave recurrence, CONSOLIDATED BLOCKS.
// Six structures (v14-v19: occupancy 4x, barriers 32->0, code 70x, trans
// 3.5x, scheduling) all land at 47.5-49.5us. Shared invariants: (a) busy
// accounting closes at 2.4GHz with SIMD idle 58%; (b) physical dep-chain is
// only ~2.7us; (c) OccupancyPercent is ~60% of requested in EVERY version;
// (d) every version launched exactly 2048 WGs. Theory: command-processor
// dispatch ramp/tail over 2048 tiny WGs is ~40% of the wall.
// v20: 512 WGs x 256 thr. Each block stages 64 batches; each of its 4 waves
// runs one independent 16-batch chain (v18 body verbatim: barrier-free,
// rolled, W-row permutation, shared-denominator trans activations).
// Steady-state per-CU residency unchanged (8 waves/CU, 2/SIMD) -> clean
// discriminator: flat result kills the ramp theory.
//
// LDS: X @ 0: 64 rows x 1072B = 68608 (row b = batch blockIdx*64+b;
//      wave w owns rows 16w..16w+15, staged by wave w itself).
//      Z @ 68608: 32B zeros. fc2 scratch (4 waves x 16 x 144B) overlays X.
#define XSTRIDE 1072
#define ZOFF    (64 * XSTRIDE)
#define LDS_BYTES (ZOFF + 32)

typedef _Float16 f16x8 __attribute__((ext_vector_type(8)));
typedef __fp16   fp16x2 __attribute__((ext_vector_type(2)));
typedef float    f32x4 __attribute__((ext_vector_type(4)));
typedef float    f32x2 __attribute__((ext_vector_type(2)));

#define LOG2E     1.44269504088896f
#define TWO_LOG2E 2.88539008177793f

__global__ __launch_bounds__(256, 2)
void lstm_fused(const int* __restrict__ objs,
                const float* __restrict__ boxes,
                const int* __restrict__ preds,
                const int* __restrict__ subj,
                const float* __restrict__ obj_emb,
                const float* __restrict__ pred_emb,
                const float* __restrict__ W_ih,
                const float* __restrict__ W_hh,
                const float* __restrict__ b_ih,
                const float* __restrict__ b_hh,
                const float* __restrict__ fc2_W,
                const float* __restrict__ fc2_b,
                float* __restrict__ out)
{
    extern __shared__ char smem[];
    const int tid  = threadIdx.x;        // 0..255
    const int wv   = tid >> 6;           // 0..3: which 16-batch problem
    const int lane = tid & 63;
    const int quad = lane >> 4;          // 0..3: K-slice of MFMA frags
    const int cidx = lane & 15;          // batch column within problem

    if (tid < 8) ((int*)(smem + ZOFF))[tid] = 0;

    // ---- stage x features (fp16): 256 threads stage 64 batches ----
    // thread tid: b = tid>>2 (0..63), j = tid&3, t = j,j+4,...,j+28.
    // NOTE: rows 16w..16w+15 are written exactly by threads of wave w.
    {
        const int b = tid >> 2;
        const int j = tid & 3;
        const long gb = (long)blockIdx.x * 64 + b;
        const int* orow = objs + gb * 32;
        const int* prow = preds + gb * 32;
        const int* srow = subj + gb * 32;
        const float* brow = boxes + gb * 128;
        char* xrow = smem + b * XSTRIDE;
        #pragma unroll
        for (int tt = 0; tt < 8; ++tt) {
            int t = j + tt * 4;
            int o = orow[t], p = prow[t], sv = srow[t];
            const float* eo = obj_emb + o * 5;
            const float* ep = pred_emb + p * 5;
            float4 bx = *(const float4*)(brow + t * 4);
            f16x8 lo, hi;
            lo[0]=(_Float16)eo[0]; lo[1]=(_Float16)eo[1]; lo[2]=(_Float16)eo[2];
            lo[3]=(_Float16)eo[3]; lo[4]=(_Float16)eo[4];
            lo[5]=(_Float16)ep[0]; lo[6]=(_Float16)ep[1]; lo[7]=(_Float16)ep[2];
            hi[0]=(_Float16)ep[3]; hi[1]=(_Float16)ep[4];
            hi[2]=(_Float16)(sv==0 ? 1.0f : 0.0f);
            hi[3]=(_Float16)(sv==1 ? 1.0f : 0.0f);
            hi[4]=(_Float16)bx.x; hi[5]=(_Float16)bx.y;
            hi[6]=(_Float16)bx.z; hi[7]=(_Float16)bx.w;
            *(f16x8*)(xrow + t * 32)      = lo;
            *(f16x8*)(xrow + t * 32 + 16) = hi;
        }
    }

    // ---- W fragments + bias (identical for all waves) ----
    f16x8 WH[8], WX[8];
    f32x4 bias[8];
    #pragma unroll
    for (int a = 0; a < 8; ++a) {
        const int gate = a >> 1;
        const float scale = (gate == 2) ? TWO_LOG2E : -LOG2E;
        const int n = gate * 32 + 8 * (cidx >> 2) + 4 * (a & 1) + (cidx & 3);
        const float* wr = W_hh + n * 32 + quad * 8;
        float4 w0 = *(const float4*)(wr);
        float4 w1 = *(const float4*)(wr + 4);
        f16x8 h8;
        h8[0]=(_Float16)(w0.x*scale); h8[1]=(_Float16)(w0.y*scale);
        h8[2]=(_Float16)(w0.z*scale); h8[3]=(_Float16)(w0.w*scale);
        h8[4]=(_Float16)(w1.x*scale); h8[5]=(_Float16)(w1.y*scale);
        h8[6]=(_Float16)(w1.z*scale); h8[7]=(_Float16)(w1.w*scale);
        WH[a] = h8;
        f16x8 x8;
        if (quad < 2) {
            const float* xr = W_ih + n * 16 + quad * 8;
            float4 u0 = *(const float4*)(xr);
            float4 u1 = *(const float4*)(xr + 4);
            x8[0]=(_Float16)(u0.x*scale); x8[1]=(_Float16)(u0.y*scale);
            x8[2]=(_Float16)(u0.z*scale); x8[3]=(_Float16)(u0.w*scale);
            x8[4]=(_Float16)(u1.x*scale); x8[5]=(_Float16)(u1.y*scale);
            x8[6]=(_Float16)(u1.z*scale); x8[7]=(_Float16)(u1.w*scale);
        } else {
            #pragma unroll
            for (int jj = 0; jj < 8; ++jj) x8[jj] = (_Float16)0.0f;
        }
        WX[a] = x8;
        const int nb = gate * 32 + 8 * quad + 4 * (a & 1);
        float4 bi = *(const float4*)(b_ih + nb);
        float4 bh = *(const float4*)(b_hh + nb);
        f32x4 bb = {(bi.x+bh.x)*scale, (bi.y+bh.y)*scale,
                    (bi.z+bh.z)*scale, (bi.w+bh.w)*scale};
        bias[a] = bb;
    }

    __syncthreads();   // Z zeros (+ staging, though wave-local) visible

    // ---- recurrence: barrier-free, rolled; wave wv owns rows 16wv+cidx ----
    const bool qlow = (quad < 2);
    int xaddr = qlow ? ((wv * 16 + cidx) * XSTRIDE + quad * 16) : ZOFF;
    const int xinc = qlow ? 32 : 0;

    f16x8 xfrag = *(const f16x8*)(smem + xaddr); xaddr += xinc;
    f32x4 accp[8];
    #pragma unroll
    for (int a = 0; a < 8; ++a)
        accp[a] = __builtin_amdgcn_mfma_f32_16x16x32_f16(WX[a], xfrag, bias[a], 0, 0, 0);

    union { int i[4]; f16x8 v; } hf;
    hf.i[0]=0; hf.i[1]=0; hf.i[2]=0; hf.i[3]=0;
    const f32x2 zz = {0.0f, 0.0f};
    f32x2 cst[4] = {zz, zz, zz, zz};
    f32x2 hv[4];
    const f32x2 one = {1.0f, 1.0f};

    #pragma unroll 1
    for (int t = 0; t < 32; ++t) {
        f32x4 acc[8];
        #pragma unroll
        for (int a = 0; a < 8; ++a)
            acc[a] = __builtin_amdgcn_mfma_f32_16x16x32_f16(WH[a], hf.v, accp[a], 0, 0, 0);

        f16x8 xn = *(const f16x8*)(smem + xaddr); xaddr += xinc;

        #pragma unroll
        for (int cc = 0; cc < 4; ++cc) {
            const int sel = cc >> 1;
            const int r0  = (cc & 1) << 1;
            f32x2 zi = {acc[0+sel][r0], acc[0+sel][r0+1]};
            f32x2 zf = {acc[2+sel][r0], acc[2+sel][r0+1]};
            f32x2 zg = {acc[4+sel][r0], acc[4+sel][r0+1]};
            f32x2 zo = {acc[6+sel][r0], acc[6+sel][r0+1]};
            f32x2 Ei = {__builtin_amdgcn_exp2f(zi.x), __builtin_amdgcn_exp2f(zi.y)};
            f32x2 Ef = {__builtin_amdgcn_exp2f(zf.x), __builtin_amdgcn_exp2f(zf.y)};
            f32x2 Eg = {__builtin_amdgcn_exp2f(zg.x), __builtin_amdgcn_exp2f(zg.y)};
            f32x2 Eo = {__builtin_amdgcn_exp2f(zo.x), __builtin_amdgcn_exp2f(zo.y)};
            f32x2 t1  = Ei + one;
            f32x2 dig = t1 * Eg + t1;                 // (1+Ei)(1+Eg)
            f32x2 tf  = Ef + one;
            f32x2 nn  = (Eg - one) * tf + cst[cc] * dig;
            f32x2 den = tf * dig;
            f32x2 rde = {__builtin_amdgcn_rcpf(den.x), __builtin_amdgcn_rcpf(den.y)};
            f32x2 c   = nn * rde;
            cst[cc] = c;
            f32x2 cl  = c * TWO_LOG2E;
            f32x2 Ec  = {__builtin_amdgcn_exp2f(cl.x), __builtin_amdgcn_exp2f(cl.y)};
            f32x2 to  = Eo + one;
            f32x2 dh  = to * Ec + to;                 // (1+Eo)(1+Ec)
            f32x2 rdh = {__builtin_amdgcn_rcpf(dh.x), __builtin_amdgcn_rcpf(dh.y)};
            hv[cc] = (Ec - one) * rdh;
            union { fp16x2 h; int i; } pk;
            pk.h = __builtin_amdgcn_cvt_pkrtz(hv[cc].x, hv[cc].y);
            hf.i[cc] = pk.i;
        }

        #pragma unroll
        for (int a = 0; a < 8; ++a)
            accp[a] = __builtin_amdgcn_mfma_f32_16x16x32_f16(WX[a], xn, bias[a], 0, 0, 0);
    }

    // ---- fc2 epilogue: per-wave scratch (overlays X after full barrier) ----
    __syncthreads();   // all waves done with X before overlay
    {
        char* s0 = smem + wv * 2304 + cidx * 144 + quad * 32;
        float4 lo4 = {hv[0].x, hv[0].y, hv[1].x, hv[1].y};
        float4 hi4 = {hv[2].x, hv[2].y, hv[3].x, hv[3].y};
        *(float4*)s0        = lo4;
        *(float4*)(s0 + 16) = hi4;
    }
    __syncthreads();
    {
        const int b = lane >> 2, j = lane & 3;   // 64 outputs per wave
        const float* hrow = (const float*)(smem + wv * 2304 + b * 144);
        const float* fw = fc2_W + j * 32;
        float s = fc2_b[j];
        #pragma unroll
        for (int k = 0; k < 8; ++k) {
            float4 hvv = *(const float4*)(hrow + k * 4);
            float4 wv4 = *(const float4*)(fw + k * 4);
            s += wv4.x*hvv.x + wv4.y*hvv.y + wv4.z*hvv.z + wv4.w*hvv.w;
        }
        s = fminf(fmaxf(s, 0.0f), 1.0f);
        out[(long)blockIdx.x * 256 + wv * 64 + lane] = s;
    }
}

extern "C" void kernel_launch(void* const* d_in, const int* in_sizes, int n_in,
                              void* d_out, int out_size, void* d_ws, size_t ws_size,
                              hipStream_t stream)
{
    // inputs: 0 objs(i32) 1 boxes(f32) 2 preds(i32) 3 subj(i32) 4 target(unused)
    //         5 obj_emb 6 pred_emb 7 W_ih 8 W_hh 9 b_ih 10 b_hh 11 fc2_W 12 fc2_b
    lstm_fused<<<512, 256, LDS_BYTES, stream>>>(
        (const int*)d_in[0], (const float*)d_in[1], (const int*)d_in[2],
        (const int*)d_in[3],
        (const float*)d_in[5], (const float*)d_in[6],
        (const float*)d_in[7], (const float*)d_in[8],
        (const float*)d_in[9], (const float*)d_in[10],
        (const float*)d_in[11], (const float*)d_in[12],
        (float*)d_out);
}